// Round 4
// baseline (412.727 us; speedup 1.0000x reference)
//
#include <hip/hip_runtime.h>
#include <hip/hip_bf16.h>

// BERT layer: B=8,S=512,H=768,NH=12,DH=64,FF=3072. Inputs fp32 (per reference), mask int32, out fp32.
// Compute core: bf16 MFMA with fp32 accumulation; fp32 residual carry.
#define H_DIM 768
#define FF_DIM 3072
#define NHEAD 12
#define DHEAD 64
#define SEQ 512
#define TOK 4096

typedef __bf16 bf16;
using bf16x8 = __attribute__((ext_vector_type(8))) __bf16;
using f32x4  = __attribute__((ext_vector_type(4))) float;

static __device__ __forceinline__ f32x4 mfma16(bf16x8 a, bf16x8 b, f32x4 c) {
  return __builtin_amdgcn_mfma_f32_16x16x32_bf16(a, b, c, 0, 0, 0);
}

// ---------------- fp32 -> bf16 conversion (n divisible by 8) ----------------
__global__ __launch_bounds__(256) void cvt_k(const float* __restrict__ in, bf16* __restrict__ out, int n) {
  int i = (blockIdx.x * 256 + threadIdx.x) * 8;
  if (i >= n) return;
  float4 a = *(const float4*)(in + i);
  float4 b = *(const float4*)(in + i + 4);
  bf16x8 o;
  o[0] = (bf16)a.x; o[1] = (bf16)a.y; o[2] = (bf16)a.z; o[3] = (bf16)a.w;
  o[4] = (bf16)b.x; o[5] = (bf16)b.y; o[6] = (bf16)b.z; o[7] = (bf16)b.w;
  *(bf16x8*)(out + i) = o;
}

// ---------------- GEMM: C[M,N] = A[M,K](bf16) * W[K,N](bf16) (+bias fp32, +gelu, +res fp32) ----
struct GemmArgs {
  const bf16* A;
  const bf16* W[3];
  const float* bias[3];
  bf16* outB[3];
  float* outF[3];
  const float* resF[3];
  int M, N, K, act;
};

#define BM 128
#define BN 128
#define BK 32
#define LPAD 40  // LDS row stride (elements): 80B, 16B-aligned rows for b128

__global__ __launch_bounds__(256) void gemm_k(GemmArgs args) {
  __shared__ bf16 As[BM][LPAD];
  __shared__ bf16 Bs[BN][LPAD];   // Bs[n][k ^ swz(n)] = W[k0+k][n0+n]
  int z = blockIdx.z;
  const bf16* A = args.A;
  const bf16* W = args.W[z];
  int Kd = args.K, N = args.N;
  int m0 = blockIdx.y * BM, n0 = blockIdx.x * BN;
  int t = threadIdx.x;
  int wid = t >> 6, lane = t & 63, quad = lane >> 4, l16 = lane & 15;
  int wm = wid >> 1, wn = wid & 1;

  f32x4 zero4 = {0.0f, 0.0f, 0.0f, 0.0f};
  f32x4 acc[4][4];
#pragma unroll
  for (int mi = 0; mi < 4; mi++)
#pragma unroll
    for (int ni = 0; ni < 4; ni++) acc[mi][ni] = zero4;

  // A staging: thread -> half-row (16 elems)
  int srow = t >> 1, scol = (t & 1) * 16;
  const bf16* gA = A + (size_t)(m0 + srow) * Kd + scol;
  // B staging: thread -> row k0+bk, 16 consecutive n at n0+bng*16; k-chunk XOR swizzle
  int bk = t >> 3, bng = t & 7;
  const bf16* gW = W + (size_t)bk * N + n0 + bng * 16;
  int swz = (bng & 3) << 3;
  int kks = bk ^ swz;

  for (int k0 = 0; k0 < Kd; k0 += BK) {
    __syncthreads();
    bf16x8 a0 = *(const bf16x8*)(gA + k0);
    bf16x8 a1 = *(const bf16x8*)(gA + k0 + 8);
    const bf16* gWk = gW + (size_t)k0 * N;
    bf16x8 w0 = *(const bf16x8*)gWk;
    bf16x8 w1 = *(const bf16x8*)(gWk + 8);
    *(bf16x8*)&As[srow][scol]     = a0;
    *(bf16x8*)&As[srow][scol + 8] = a1;
#pragma unroll
    for (int j = 0; j < 8; j++) {
      Bs[bng * 16 + j][kks]     = w0[j];
      Bs[bng * 16 + 8 + j][kks] = w1[j];
    }
    __syncthreads();
    bf16x8 af[4], bfr[4];
#pragma unroll
    for (int mi = 0; mi < 4; mi++) af[mi] = *(const bf16x8*)&As[wm * 64 + mi * 16 + l16][quad * 8];
#pragma unroll
    for (int ni = 0; ni < 4; ni++) {
      int nn = wn * 64 + ni * 16 + l16;
      int sw = ((nn >> 4) & 3) << 3;
      bfr[ni] = *(const bf16x8*)&Bs[nn][(quad * 8) ^ sw];
    }
#pragma unroll
    for (int mi = 0; mi < 4; mi++)
#pragma unroll
      for (int ni = 0; ni < 4; ni++) acc[mi][ni] = mfma16(af[mi], bfr[ni], acc[mi][ni]);
  }

  const float* bias = args.bias[z];
  bf16* outB = args.outB[z];
  float* outF = args.outF[z];
  const float* resF = args.resF[z];
  float bv[4];
#pragma unroll
  for (int ni = 0; ni < 4; ni++) bv[ni] = bias[n0 + wn * 64 + ni * 16 + l16];
#pragma unroll
  for (int mi = 0; mi < 4; mi++) {
#pragma unroll
    for (int r = 0; r < 4; r++) {
      int row = m0 + wm * 64 + mi * 16 + quad * 4 + r;  // C/D: row=quad*4+reg (m89-verified)
#pragma unroll
      for (int ni = 0; ni < 4; ni++) {
        int col = n0 + wn * 64 + ni * 16 + l16;
        float v = acc[mi][ni][r] + bv[ni];
        if (args.act) v = 0.5f * v * (1.0f + erff(v * 0.70710678118654752f));  // exact GELU
        size_t idx = (size_t)row * N + col;
        if (resF) v += resF[idx];
        if (outB) outB[idx] = (bf16)v;
        if (outF) outF[idx] = v;
      }
    }
  }
}

// ---------------- attention: flash-style, one block = (b,h) x 64 q-rows ----------------
#define CHK 128
__global__ __launch_bounds__(256) void attn_k(const bf16* __restrict__ Qg, const bf16* __restrict__ Kg,
                                              const bf16* __restrict__ Vg, const int* __restrict__ mask,
                                              bf16* __restrict__ ctx) {
  __shared__ bf16 Ks[CHK][72];
  __shared__ bf16 Vts[DHEAD][CHK + 8];
  __shared__ float maskadd[CHK];
  __shared__ bf16 Ps[4][16][LPAD];
  int bh = blockIdx.y;
  int b = bh / NHEAD, h = bh % NHEAD;
  int q0 = blockIdx.x * 64;
  int t = threadIdx.x;
  int wid = t >> 6, lane = t & 63, quad = lane >> 4, l16 = lane & 15;
  size_t base = (size_t)b * SEQ * H_DIM + (size_t)h * DHEAD;

  int qrow = q0 + wid * 16 + l16;
  bf16x8 qf0 = *(const bf16x8*)(Qg + base + (size_t)qrow * H_DIM + quad * 8);
  bf16x8 qf1 = *(const bf16x8*)(Qg + base + (size_t)qrow * H_DIM + 32 + quad * 8);

  f32x4 zero4 = {0.0f, 0.0f, 0.0f, 0.0f};
  f32x4 o[4];
  float m_i[4], l_i[4];
#pragma unroll
  for (int r = 0; r < 4; r++) { o[r] = zero4; m_i[r] = -1e30f; l_i[r] = 0.0f; }

  for (int c0 = 0; c0 < SEQ; c0 += CHK) {
    __syncthreads();
    {  // stage K chunk: 128 keys x 64 dh
      int row = t >> 1, half = (t & 1) * 32;
      const bf16* g = Kg + base + (size_t)(c0 + row) * H_DIM + half;
      *(bf16x8*)&Ks[row][half]      = *(const bf16x8*)g;
      *(bf16x8*)&Ks[row][half + 8]  = *(const bf16x8*)(g + 8);
      *(bf16x8*)&Ks[row][half + 16] = *(const bf16x8*)(g + 16);
      *(bf16x8*)&Ks[row][half + 24] = *(const bf16x8*)(g + 24);
    }
#pragma unroll
    for (int pass = 0; pass < 4; ++pass) {  // stage V^T chunk
      int s = (t >> 3) + pass * 32, dg = (t & 7) * 8;
      bf16x8 v = *(const bf16x8*)(Vg + base + (size_t)(c0 + s) * H_DIM + dg);
#pragma unroll
      for (int j = 0; j < 8; j++) Vts[dg + j][s] = v[j];
    }
    if (t < CHK) maskadd[t] = (1.0f - (float)mask[b * SEQ + c0 + t]) * -10000.0f;
    __syncthreads();

    for (int kt = 0; kt < CHK; kt += 32) {
      f32x4 s0 = zero4, s1 = zero4;
      bf16x8 k0a = *(const bf16x8*)&Ks[kt + l16][quad * 8];
      bf16x8 k0b = *(const bf16x8*)&Ks[kt + l16][32 + quad * 8];
      bf16x8 k1a = *(const bf16x8*)&Ks[kt + 16 + l16][quad * 8];
      bf16x8 k1b = *(const bf16x8*)&Ks[kt + 16 + l16][32 + quad * 8];
      s0 = mfma16(qf0, k0a, s0); s0 = mfma16(qf1, k0b, s0);
      s1 = mfma16(qf0, k1a, s1); s1 = mfma16(qf1, k1b, s1);
      float add0 = maskadd[kt + l16], add1 = maskadd[kt + 16 + l16];
#pragma unroll
      for (int r = 0; r < 4; r++) {
        float v0 = s0[r] * 0.125f + add0;
        float v1 = s1[r] * 0.125f + add1;
        float mx = fmaxf(v0, v1);
#pragma unroll
        for (int off = 1; off < 16; off <<= 1) mx = fmaxf(mx, __shfl_xor(mx, off));
        float mnew = fmaxf(m_i[r], mx);
        float p0 = __expf(v0 - mnew), p1 = __expf(v1 - mnew);
        float alpha = __expf(m_i[r] - mnew);
        m_i[r] = mnew;
        float ps = p0 + p1;
#pragma unroll
        for (int off = 1; off < 16; off <<= 1) ps += __shfl_xor(ps, off);
        l_i[r] = l_i[r] * alpha + ps;
#pragma unroll
        for (int ni = 0; ni < 4; ni++) o[ni][r] *= alpha;
        Ps[wid][quad * 4 + r][l16]      = (bf16)p0;
        Ps[wid][quad * 4 + r][16 + l16] = (bf16)p1;
      }
      bf16x8 pa = *(const bf16x8*)&Ps[wid][l16][quad * 8];
#pragma unroll
      for (int ni = 0; ni < 4; ni++) {
        bf16x8 vb = *(const bf16x8*)&Vts[ni * 16 + l16][kt + quad * 8];
        o[ni] = mfma16(pa, vb, o[ni]);
      }
    }
  }
#pragma unroll
  for (int r = 0; r < 4; r++) {
    int row = q0 + wid * 16 + quad * 4 + r;
    float inv = 1.0f / l_i[r];
#pragma unroll
    for (int ni = 0; ni < 4; ni++)
      ctx[base + (size_t)row * H_DIM + ni * 16 + l16] = (bf16)(o[ni][r] * inv);
  }
}

// ---------------- LayerNorm over H=768 (fp32 in, fp32 params; bf16/fp32 out) ----------------
__global__ __launch_bounds__(256) void ln_k(const float* __restrict__ in, const float* __restrict__ g,
                                            const float* __restrict__ bta, bf16* __restrict__ outB,
                                            float* __restrict__ outF) {
  int row = blockIdx.x, t = threadIdx.x;
  const float* x = in + (size_t)row * H_DIM;
  float v[3], s = 0.0f, sq = 0.0f;
#pragma unroll
  for (int i = 0; i < 3; i++) { v[i] = x[t + i * 256]; s += v[i]; sq += v[i] * v[i]; }
#pragma unroll
  for (int off = 32; off >= 1; off >>= 1) { s += __shfl_down(s, off); sq += __shfl_down(sq, off); }
  __shared__ float ssum[4], ssq[4], smu, srs;
  int lane = t & 63, w = t >> 6;
  if (lane == 0) { ssum[w] = s; ssq[w] = sq; }
  __syncthreads();
  if (t == 0) {
    float S = ssum[0] + ssum[1] + ssum[2] + ssum[3];
    float Q = ssq[0] + ssq[1] + ssq[2] + ssq[3];
    float mu = S * (1.0f / H_DIM);
    float var = Q * (1.0f / H_DIM) - mu * mu;
    smu = mu;
    srs = rsqrtf(var + 1e-3f);
  }
  __syncthreads();
  float mu = smu, rs = srs;
#pragma unroll
  for (int i = 0; i < 3; i++) {
    int c = t + i * 256;
    float y = (v[i] - mu) * rs * g[c] + bta[c];
    if (outB) outB[(size_t)row * H_DIM + c] = (bf16)y;
    if (outF) outF[(size_t)row * H_DIM + c] = y;
  }
}

extern "C" void kernel_launch(void* const* d_in, const int* in_sizes, int n_in,
                              void* d_out, int out_size, void* d_ws, size_t ws_size,
                              hipStream_t stream) {
  const float* x    = (const float*)d_in[0];
  const int*   mask = (const int*)d_in[1];
  const float* Wq = (const float*)d_in[2];  const float* bq = (const float*)d_in[3];
  const float* Wk = (const float*)d_in[4];  const float* bk = (const float*)d_in[5];
  const float* Wv = (const float*)d_in[6];  const float* bv = (const float*)d_in[7];
  const float* Wo = (const float*)d_in[8];  const float* bo = (const float*)d_in[9];
  const float* ln1g = (const float*)d_in[10]; const float* ln1b = (const float*)d_in[11];
  const float* W1 = (const float*)d_in[12]; const float* b1 = (const float*)d_in[13];
  const float* W2 = (const float*)d_in[14]; const float* b2 = (const float*)d_in[15];
  const float* ln2g = (const float*)d_in[16]; const float* ln2b = (const float*)d_in[17];
  float* out = (float*)d_out;
  (void)ws_size; (void)in_sizes; (void)n_in; (void)out_size;

  // ---- workspace layout with lifetime aliasing; peak 64,487,424 B ≈ 61.5 MiB ----
  char* w = (char*)d_ws;
  const size_t SZ_TH  = (size_t)TOK * H_DIM * 2;      // 6,291,456  bf16 token x H
  const size_t SZ_W   = (size_t)H_DIM * H_DIM * 2;    // 1,179,648  bf16 HxH weight
  const size_t SZ_WF  = (size_t)H_DIM * FF_DIM * 2;   // 4,718,592  bf16 HxFF weight
  bf16* xB  = (bf16*)(w);                              // [0, 6.29M)     dead after QKV
  bf16* WqB = (bf16*)(w + SZ_TH);                      // [6.29M, 7.47M)
  bf16* WkB = (bf16*)(w + SZ_TH + SZ_W);
  bf16* WvB = (bf16*)(w + SZ_TH + 2 * SZ_W);
  bf16* WoB = (bf16*)(w + SZ_TH + 3 * SZ_W);
  bf16* W1B = (bf16*)(w + SZ_TH + 4 * SZ_W);           // [11.0M, 15.7M) dead after FF1
  bf16* W2B = (bf16*)(w + SZ_TH + 4 * SZ_W + SZ_WF);   // [15.7M, 20.4M)
  char* pQ  = w + SZ_TH + 4 * SZ_W + 2 * SZ_WF;        // 20,447,232
  bf16* QB  = (bf16*)(pQ);                             // [20.4M, 26.7M) dead after attn
  bf16* KB  = (bf16*)(pQ + SZ_TH);                     // [26.7M, 33.0M) dead after attn
  bf16* VB  = (bf16*)(pQ + 2 * SZ_TH);                 // [33.0M, 39.3M) dead after attn
  bf16* CTX = (bf16*)(pQ + 3 * SZ_TH);                 // [39.3M, 45.6M) dead after Wo
  float* PRE1 = (float*)(pQ + 4 * SZ_TH);              // [45.6M, 58.2M) fp32, dead after LN1
  bf16* H1   = QB;                                     // alias QB
  float* H1F = (float*)(pQ + SZ_TH);                   // alias KB+VB (fp32 12.6M)
  bf16* FFA  = CTX;                                    // [39.3M, 64.5M): CTX + PRE1 + 6.3M
  float* PRE2 = (float*)(w);                           // [0, 12.6M): xB + Wq..Wo + part of W1B (all dead)

  dim3 tb(256);

  // fp32 -> bf16 conversions
  cvt_k<<<(TOK * H_DIM) / (256 * 8), tb, 0, stream>>>(x, xB, TOK * H_DIM);
  cvt_k<<<(H_DIM * H_DIM) / (256 * 8), tb, 0, stream>>>(Wq, WqB, H_DIM * H_DIM);
  cvt_k<<<(H_DIM * H_DIM) / (256 * 8), tb, 0, stream>>>(Wk, WkB, H_DIM * H_DIM);
  cvt_k<<<(H_DIM * H_DIM) / (256 * 8), tb, 0, stream>>>(Wv, WvB, H_DIM * H_DIM);
  cvt_k<<<(H_DIM * H_DIM) / (256 * 8), tb, 0, stream>>>(Wo, WoB, H_DIM * H_DIM);
  cvt_k<<<(H_DIM * FF_DIM) / (256 * 8), tb, 0, stream>>>(W1, W1B, H_DIM * FF_DIM);
  cvt_k<<<(H_DIM * FF_DIM) / (256 * 8), tb, 0, stream>>>(W2, W2B, H_DIM * FF_DIM);

  // fused QKV projection
  GemmArgs ga = {};
  ga.A = xB; ga.M = TOK; ga.N = H_DIM; ga.K = H_DIM; ga.act = 0;
  ga.W[0] = WqB; ga.W[1] = WkB; ga.W[2] = WvB;
  ga.bias[0] = bq; ga.bias[1] = bk; ga.bias[2] = bv;
  ga.outB[0] = QB; ga.outB[1] = KB; ga.outB[2] = VB;
  gemm_k<<<dim3(H_DIM / BN, TOK / BM, 3), tb, 0, stream>>>(ga);

  // attention
  attn_k<<<dim3(SEQ / 64, 8 * NHEAD), tb, 0, stream>>>(QB, KB, VB, mask, CTX);

  // Wo projection + residual(x fp32) -> PRE1 (fp32)
  GemmArgs go = {};
  go.A = CTX; go.M = TOK; go.N = H_DIM; go.K = H_DIM; go.act = 0;
  go.W[0] = WoB; go.bias[0] = bo; go.resF[0] = x; go.outF[0] = PRE1;
  gemm_k<<<dim3(H_DIM / BN, TOK / BM, 1), tb, 0, stream>>>(go);

  ln_k<<<TOK, tb, 0, stream>>>(PRE1, ln1g, ln1b, H1, H1F);

  // FF1 + GELU
  GemmArgs g1 = {};
  g1.A = H1; g1.M = TOK; g1.N = FF_DIM; g1.K = H_DIM; g1.act = 1;
  g1.W[0] = W1B; g1.bias[0] = b1; g1.outB[0] = FFA;
  gemm_k<<<dim3(FF_DIM / BN, TOK / BM, 1), tb, 0, stream>>>(g1);

  // FF2 + residual(H1F fp32) -> PRE2 (fp32)
  GemmArgs g2 = {};
  g2.A = FFA; g2.M = TOK; g2.N = H_DIM; g2.K = FF_DIM; g2.act = 0;
  g2.W[0] = W2B; g2.bias[0] = b2; g2.resF[0] = H1F; g2.outF[0] = PRE2;
  gemm_k<<<dim3(H_DIM / BN, TOK / BM, 1), tb, 0, stream>>>(g2);

  ln_k<<<TOK, tb, 0, stream>>>(PRE2, ln2g, ln2b, nullptr, out);
}

// Round 5
// 335.344 us; speedup vs baseline: 1.2308x; 1.2308x over previous
//
#include <hip/hip_runtime.h>
#include <hip/hip_bf16.h>

// BERT layer: B=8,S=512,H=768,NH=12,DH=64,FF=3072. Inputs fp32, mask int32, out fp32.
// Core: bf16 MFMA, fp32 accum, fp32 residual carry. Weights pre-transposed+converted once.
#define H_DIM 768
#define FF_DIM 3072
#define NHEAD 12
#define DHEAD 64
#define SEQ 512
#define TOK 4096

typedef __bf16 bf16;
using bf16x8 = __attribute__((ext_vector_type(8))) __bf16;
using f32x4  = __attribute__((ext_vector_type(4))) float;

static __device__ __forceinline__ f32x4 mfma16(bf16x8 a, bf16x8 b, f32x4 c) {
  return __builtin_amdgcn_mfma_f32_16x16x32_bf16(a, b, c, 0, 0, 0);
}

// ---------------- fp32 -> bf16 conversion (n divisible by 2048) ----------------
__global__ __launch_bounds__(256) void cvt_k(const float* __restrict__ in, bf16* __restrict__ out, int n) {
  int i = (blockIdx.x * 256 + threadIdx.x) * 8;
  if (i >= n) return;
  float4 a = *(const float4*)(in + i);
  float4 b = *(const float4*)(in + i + 4);
  bf16x8 o;
  o[0] = (bf16)a.x; o[1] = (bf16)a.y; o[2] = (bf16)a.z; o[3] = (bf16)a.w;
  o[4] = (bf16)b.x; o[5] = (bf16)b.y; o[6] = (bf16)b.z; o[7] = (bf16)b.w;
  *(bf16x8*)(out + i) = o;
}

// ---------------- fused transpose+convert: fp32 in[R][C] -> bf16 out[C][R] ----------------
__global__ __launch_bounds__(256) void cvtT_k(const float* __restrict__ in, bf16* __restrict__ out,
                                              int R, int C) {
  __shared__ bf16 tile[32][33];
  int c0 = blockIdx.x * 32, r0 = blockIdx.y * 32;
  int tx = threadIdx.x & 31, ty = threadIdx.x >> 5;  // 32 x 8
  for (int i = 0; i < 32; i += 8) tile[ty + i][tx] = (bf16)in[(size_t)(r0 + ty + i) * C + c0 + tx];
  __syncthreads();
  for (int i = 0; i < 32; i += 8) out[(size_t)(c0 + ty + i) * R + r0 + tx] = tile[tx][ty + i];
}

// ---------------- GEMM: C[M,N] = A[M,K](bf16) * Bt[N,K](bf16)^T (+bias fp32, +gelu, +res fp32) ----
struct GemmArgs {
  const bf16* A;
  const bf16* W[3];      // transposed weights [N][K]
  const float* bias[3];
  bf16* outB[3];
  float* outF[3];
  const float* resF[3];
  int M, N, K, act;
};

#define BK 32
#define LPAD 40  // LDS row stride (elements): 80 B, 16B-aligned rows, 2-way-max (free) b128 conflicts

// Wave grid fixed 2x2. Wave tile = (MI*16) x (NI*16). BM = MI*32, BN = NI*32.
template <int BM, int BN, int MI, int NI>
__global__ __launch_bounds__(256) void gemm_t(GemmArgs args) {
  __shared__ bf16 As[BM][LPAD];
  __shared__ bf16 Bs[BN][LPAD];
  int z = blockIdx.z;
  const bf16* A  = args.A;
  const bf16* Bt = args.W[z];
  int Kd = args.K, N = args.N;
  int m0 = blockIdx.y * BM, n0 = blockIdx.x * BN;
  int t = threadIdx.x;
  int wid = t >> 6, lane = t & 63, quad = lane >> 4, l16 = lane & 15;
  int wm = wid >> 1, wn = wid & 1;

  f32x4 zero4 = {0.0f, 0.0f, 0.0f, 0.0f};
  f32x4 acc[MI][NI];
#pragma unroll
  for (int mi = 0; mi < MI; mi++)
#pragma unroll
    for (int ni = 0; ni < NI; ni++) acc[mi][ni] = zero4;

  constexpr int APT = BM * BK / 256;  // elems staged per thread for A (16 or 8)
  constexpr int BPT = BN * BK / 256;
  int arow, acol, brow, bcol;
  if constexpr (APT == 16) { arow = t >> 1; acol = (t & 1) * 16; }
  else                     { arow = t >> 2; acol = (t & 3) * 8; }
  if constexpr (BPT == 16) { brow = t >> 1; bcol = (t & 1) * 16; }
  else                     { brow = t >> 2; bcol = (t & 3) * 8; }
  const bf16* gA = A  + (size_t)(m0 + arow) * Kd + acol;
  const bf16* gB = Bt + (size_t)(n0 + brow) * Kd + bcol;

  for (int k0 = 0; k0 < Kd; k0 += BK) {
    bf16x8 a0, a1, b0, b1;
    a0 = *(const bf16x8*)(gA + k0);
    if constexpr (APT == 16) a1 = *(const bf16x8*)(gA + k0 + 8);
    b0 = *(const bf16x8*)(gB + k0);
    if constexpr (BPT == 16) b1 = *(const bf16x8*)(gB + k0 + 8);
    __syncthreads();
    *(bf16x8*)&As[arow][acol] = a0;
    if constexpr (APT == 16) *(bf16x8*)&As[arow][acol + 8] = a1;
    *(bf16x8*)&Bs[brow][bcol] = b0;
    if constexpr (BPT == 16) *(bf16x8*)&Bs[brow][bcol + 8] = b1;
    __syncthreads();
    bf16x8 af[MI], bfr[NI];
#pragma unroll
    for (int mi = 0; mi < MI; mi++) af[mi] = *(const bf16x8*)&As[wm * (MI * 16) + mi * 16 + l16][quad * 8];
#pragma unroll
    for (int ni = 0; ni < NI; ni++) bfr[ni] = *(const bf16x8*)&Bs[wn * (NI * 16) + ni * 16 + l16][quad * 8];
#pragma unroll
    for (int mi = 0; mi < MI; mi++)
#pragma unroll
      for (int ni = 0; ni < NI; ni++) acc[mi][ni] = mfma16(af[mi], bfr[ni], acc[mi][ni]);
  }

  const float* bias = args.bias[z];
  bf16* outB = args.outB[z];
  float* outF = args.outF[z];
  const float* resF = args.resF[z];
  float bv[NI];
#pragma unroll
  for (int ni = 0; ni < NI; ni++) bv[ni] = bias[n0 + wn * (NI * 16) + ni * 16 + l16];
#pragma unroll
  for (int mi = 0; mi < MI; mi++) {
#pragma unroll
    for (int r = 0; r < 4; r++) {
      int row = m0 + wm * (MI * 16) + mi * 16 + quad * 4 + r;  // C/D: row=quad*4+reg (m89-verified)
#pragma unroll
      for (int ni = 0; ni < NI; ni++) {
        int col = n0 + wn * (NI * 16) + ni * 16 + l16;
        float v = acc[mi][ni][r] + bv[ni];
        if (args.act) v = 0.5f * v * (1.0f + erff(v * 0.70710678118654752f));  // exact GELU
        size_t idx = (size_t)row * N + col;
        if (resF) v += resF[idx];
        if (outB) outB[idx] = (bf16)v;
        if (outF) outF[idx] = v;
      }
    }
  }
}

// ---------------- attention: flash-style, one block = (b,h) x 64 q-rows ----------------
#define CHK 128
__global__ __launch_bounds__(256) void attn_k(const bf16* __restrict__ Qg, const bf16* __restrict__ Kg,
                                              const bf16* __restrict__ Vg, const int* __restrict__ mask,
                                              bf16* __restrict__ ctx) {
  __shared__ bf16 Ks[CHK][72];
  __shared__ bf16 Vts[DHEAD][CHK + 8];
  __shared__ float maskadd[CHK];
  __shared__ bf16 Ps[4][16][LPAD];
  int bh = blockIdx.y;
  int b = bh / NHEAD, h = bh % NHEAD;
  int q0 = blockIdx.x * 64;
  int t = threadIdx.x;
  int wid = t >> 6, lane = t & 63, quad = lane >> 4, l16 = lane & 15;
  size_t base = (size_t)b * SEQ * H_DIM + (size_t)h * DHEAD;

  int qrow = q0 + wid * 16 + l16;
  bf16x8 qf0 = *(const bf16x8*)(Qg + base + (size_t)qrow * H_DIM + quad * 8);
  bf16x8 qf1 = *(const bf16x8*)(Qg + base + (size_t)qrow * H_DIM + 32 + quad * 8);

  f32x4 zero4 = {0.0f, 0.0f, 0.0f, 0.0f};
  f32x4 o[4];
  float m_i[4], l_i[4];
#pragma unroll
  for (int r = 0; r < 4; r++) { o[r] = zero4; m_i[r] = -1e30f; l_i[r] = 0.0f; }

  for (int c0 = 0; c0 < SEQ; c0 += CHK) {
    __syncthreads();
    {  // stage K chunk: 128 keys x 64 dh
      int row = t >> 1, half = (t & 1) * 32;
      const bf16* g = Kg + base + (size_t)(c0 + row) * H_DIM + half;
      *(bf16x8*)&Ks[row][half]      = *(const bf16x8*)g;
      *(bf16x8*)&Ks[row][half + 8]  = *(const bf16x8*)(g + 8);
      *(bf16x8*)&Ks[row][half + 16] = *(const bf16x8*)(g + 16);
      *(bf16x8*)&Ks[row][half + 24] = *(const bf16x8*)(g + 24);
    }
#pragma unroll
    for (int pass = 0; pass < 4; ++pass) {  // stage V^T chunk
      int s = (t >> 3) + pass * 32, dg = (t & 7) * 8;
      bf16x8 v = *(const bf16x8*)(Vg + base + (size_t)(c0 + s) * H_DIM + dg);
#pragma unroll
      for (int j = 0; j < 8; j++) Vts[dg + j][s] = v[j];
    }
    if (t < CHK) maskadd[t] = (1.0f - (float)mask[b * SEQ + c0 + t]) * -10000.0f;
    __syncthreads();

    for (int kt = 0; kt < CHK; kt += 32) {
      f32x4 s0 = zero4, s1 = zero4;
      bf16x8 k0a = *(const bf16x8*)&Ks[kt + l16][quad * 8];
      bf16x8 k0b = *(const bf16x8*)&Ks[kt + l16][32 + quad * 8];
      bf16x8 k1a = *(const bf16x8*)&Ks[kt + 16 + l16][quad * 8];
      bf16x8 k1b = *(const bf16x8*)&Ks[kt + 16 + l16][32 + quad * 8];
      s0 = mfma16(qf0, k0a, s0); s0 = mfma16(qf1, k0b, s0);
      s1 = mfma16(qf0, k1a, s1); s1 = mfma16(qf1, k1b, s1);
      float add0 = maskadd[kt + l16], add1 = maskadd[kt + 16 + l16];
#pragma unroll
      for (int r = 0; r < 4; r++) {
        float v0 = s0[r] * 0.125f + add0;
        float v1 = s1[r] * 0.125f + add1;
        float mx = fmaxf(v0, v1);
#pragma unroll
        for (int off = 1; off < 16; off <<= 1) mx = fmaxf(mx, __shfl_xor(mx, off));
        float mnew = fmaxf(m_i[r], mx);
        float p0 = __expf(v0 - mnew), p1 = __expf(v1 - mnew);
        float alpha = __expf(m_i[r] - mnew);
        m_i[r] = mnew;
        float ps = p0 + p1;
#pragma unroll
        for (int off = 1; off < 16; off <<= 1) ps += __shfl_xor(ps, off);
        l_i[r] = l_i[r] * alpha + ps;
#pragma unroll
        for (int ni = 0; ni < 4; ni++) o[ni][r] *= alpha;
        Ps[wid][quad * 4 + r][l16]      = (bf16)p0;
        Ps[wid][quad * 4 + r][16 + l16] = (bf16)p1;
      }
      bf16x8 pa = *(const bf16x8*)&Ps[wid][l16][quad * 8];
#pragma unroll
      for (int ni = 0; ni < 4; ni++) {
        bf16x8 vb = *(const bf16x8*)&Vts[ni * 16 + l16][kt + quad * 8];
        o[ni] = mfma16(pa, vb, o[ni]);
      }
    }
  }
#pragma unroll
  for (int r = 0; r < 4; r++) {
    int row = q0 + wid * 16 + quad * 4 + r;
    float inv = 1.0f / l_i[r];
#pragma unroll
    for (int ni = 0; ni < 4; ni++)
      ctx[base + (size_t)row * H_DIM + ni * 16 + l16] = (bf16)(o[ni][r] * inv);
  }
}

// ---------------- LayerNorm over H=768 (fp32 in, fp32 params; bf16/fp32 out) ----------------
__global__ __launch_bounds__(256) void ln_k(const float* __restrict__ in, const float* __restrict__ g,
                                            const float* __restrict__ bta, bf16* __restrict__ outB,
                                            float* __restrict__ outF) {
  int row = blockIdx.x, t = threadIdx.x;
  const float* x = in + (size_t)row * H_DIM;
  float v[3], s = 0.0f, sq = 0.0f;
#pragma unroll
  for (int i = 0; i < 3; i++) { v[i] = x[t + i * 256]; s += v[i]; sq += v[i] * v[i]; }
#pragma unroll
  for (int off = 32; off >= 1; off >>= 1) { s += __shfl_down(s, off); sq += __shfl_down(sq, off); }
  __shared__ float ssum[4], ssq[4], smu, srs;
  int lane = t & 63, w = t >> 6;
  if (lane == 0) { ssum[w] = s; ssq[w] = sq; }
  __syncthreads();
  if (t == 0) {
    float S = ssum[0] + ssum[1] + ssum[2] + ssum[3];
    float Q = ssq[0] + ssq[1] + ssq[2] + ssq[3];
    float mu = S * (1.0f / H_DIM);
    float var = Q * (1.0f / H_DIM) - mu * mu;
    smu = mu;
    srs = rsqrtf(var + 1e-3f);
  }
  __syncthreads();
  float mu = smu, rs = srs;
#pragma unroll
  for (int i = 0; i < 3; i++) {
    int c = t + i * 256;
    float y = (v[i] - mu) * rs * g[c] + bta[c];
    if (outB) outB[(size_t)row * H_DIM + c] = (bf16)y;
    if (outF) outF[(size_t)row * H_DIM + c] = y;
  }
}

extern "C" void kernel_launch(void* const* d_in, const int* in_sizes, int n_in,
                              void* d_out, int out_size, void* d_ws, size_t ws_size,
                              hipStream_t stream) {
  const float* x    = (const float*)d_in[0];
  const int*   mask = (const int*)d_in[1];
  const float* Wq = (const float*)d_in[2];  const float* bq = (const float*)d_in[3];
  const float* Wk = (const float*)d_in[4];  const float* bk = (const float*)d_in[5];
  const float* Wv = (const float*)d_in[6];  const float* bv = (const float*)d_in[7];
  const float* Wo = (const float*)d_in[8];  const float* bo = (const float*)d_in[9];
  const float* ln1g = (const float*)d_in[10]; const float* ln1b = (const float*)d_in[11];
  const float* W1 = (const float*)d_in[12]; const float* b1 = (const float*)d_in[13];
  const float* W2 = (const float*)d_in[14]; const float* b2 = (const float*)d_in[15];
  const float* ln2g = (const float*)d_in[16]; const float* ln2b = (const float*)d_in[17];
  float* out = (float*)d_out;
  (void)ws_size; (void)in_sizes; (void)n_in; (void)out_size;

  // ---- workspace layout with lifetime aliasing; peak ≈ 61.5 MiB ----
  char* w = (char*)d_ws;
  const size_t SZ_TH  = (size_t)TOK * H_DIM * 2;      // 6,291,456  bf16 token x H
  const size_t SZ_W   = (size_t)H_DIM * H_DIM * 2;    // 1,179,648  bf16 HxH weight
  const size_t SZ_WF  = (size_t)H_DIM * FF_DIM * 2;   // 4,718,592  bf16 HxFF weight
  bf16* xB  = (bf16*)(w);                              // dead after QKV
  bf16* WqT = (bf16*)(w + SZ_TH);                      // transposed [N][K]
  bf16* WkT = (bf16*)(w + SZ_TH + SZ_W);
  bf16* WvT = (bf16*)(w + SZ_TH + 2 * SZ_W);
  bf16* WoT = (bf16*)(w + SZ_TH + 3 * SZ_W);
  bf16* W1T = (bf16*)(w + SZ_TH + 4 * SZ_W);           // dead after FF1
  bf16* W2T = (bf16*)(w + SZ_TH + 4 * SZ_W + SZ_WF);
  char* pQ  = w + SZ_TH + 4 * SZ_W + 2 * SZ_WF;
  bf16* QB  = (bf16*)(pQ);                             // dead after attn
  bf16* KB  = (bf16*)(pQ + SZ_TH);
  bf16* VB  = (bf16*)(pQ + 2 * SZ_TH);
  bf16* CTX = (bf16*)(pQ + 3 * SZ_TH);                 // dead after Wo
  float* PRE1 = (float*)(pQ + 4 * SZ_TH);              // dead after LN1
  bf16* H1   = QB;                                     // alias QB
  float* H1F = (float*)(pQ + SZ_TH);                   // alias KB+VB
  bf16* FFA  = CTX;                                    // CTX + PRE1 + 6.3M
  float* PRE2 = (float*)(w);                           // aliases xB + WqT..WoT + part of W1T (all dead)

  dim3 tb(256);

  // conversions: x (straight), weights (transpose+convert to [N][K])
  cvt_k<<<(TOK * H_DIM) / 2048, tb, 0, stream>>>(x, xB, TOK * H_DIM);
  cvtT_k<<<dim3(24, 24), tb, 0, stream>>>(Wq, WqT, H_DIM, H_DIM);
  cvtT_k<<<dim3(24, 24), tb, 0, stream>>>(Wk, WkT, H_DIM, H_DIM);
  cvtT_k<<<dim3(24, 24), tb, 0, stream>>>(Wv, WvT, H_DIM, H_DIM);
  cvtT_k<<<dim3(24, 24), tb, 0, stream>>>(Wo, WoT, H_DIM, H_DIM);
  cvtT_k<<<dim3(96, 24), tb, 0, stream>>>(W1, W1T, H_DIM, FF_DIM);   // [768][3072] -> [3072][768]
  cvtT_k<<<dim3(24, 96), tb, 0, stream>>>(W2, W2T, FF_DIM, H_DIM);   // [3072][768] -> [768][3072]

  // fused QKV projection: 128x128 tile, grid 6x32x3 = 576 blocks
  GemmArgs ga = {};
  ga.A = xB; ga.M = TOK; ga.N = H_DIM; ga.K = H_DIM; ga.act = 0;
  ga.W[0] = WqT; ga.W[1] = WkT; ga.W[2] = WvT;
  ga.bias[0] = bq; ga.bias[1] = bk; ga.bias[2] = bv;
  ga.outB[0] = QB; ga.outB[1] = KB; ga.outB[2] = VB;
  gemm_t<128, 128, 4, 4><<<dim3(H_DIM / 128, TOK / 128, 3), tb, 0, stream>>>(ga);

  // attention: 768 blocks
  attn_k<<<dim3(SEQ / 64, 8 * NHEAD), tb, 0, stream>>>(QB, KB, VB, mask, CTX);

  // Wo projection + residual(x fp32) -> PRE1: 64x64 tile, grid 12x64 = 768 blocks
  GemmArgs go = {};
  go.A = CTX; go.M = TOK; go.N = H_DIM; go.K = H_DIM; go.act = 0;
  go.W[0] = WoT; go.bias[0] = bo; go.resF[0] = x; go.outF[0] = PRE1;
  gemm_t<64, 64, 2, 2><<<dim3(H_DIM / 64, TOK / 64, 1), tb, 0, stream>>>(go);

  ln_k<<<TOK, tb, 0, stream>>>(PRE1, ln1g, ln1b, H1, H1F);

  // FF1 + GELU: 128x128 tile, grid 24x32 = 768 blocks
  GemmArgs g1 = {};
  g1.A = H1; g1.M = TOK; g1.N = FF_DIM; g1.K = H_DIM; g1.act = 1;
  g1.W[0] = W1T; g1.bias[0] = b1; g1.outB[0] = FFA;
  gemm_t<128, 128, 4, 4><<<dim3(FF_DIM / 128, TOK / 128, 1), tb, 0, stream>>>(g1);

  // FF2 + residual(H1F fp32) -> PRE2: 64x64 tile, grid 12x64 = 768 blocks
  GemmArgs g2 = {};
  g2.A = FFA; g2.M = TOK; g2.N = H_DIM; g2.K = FF_DIM; g2.act = 0;
  g2.W[0] = W2T; g2.bias[0] = b2; g2.resF[0] = H1F; g2.outF[0] = PRE2;
  gemm_t<64, 64, 2, 2><<<dim3(H_DIM / 64, TOK / 64, 1), tb, 0, stream>>>(g2);

  ln_k<<<TOK, tb, 0, stream>>>(PRE2, ln2g, ln2b, nullptr, out);
}